// Round 14
// baseline (335.853 us; speedup 1.0000x reference)
//
#include <hip/hip_runtime.h>
#include <hip/hip_bf16.h>
#include <stdint.h>

// Problem: x[128,64,1024] fp32; W1,W2 [1024,1024] fp32 (torch Linear, y = x @ W^T)
//   h = x @ W1^T ; spikes = LIF_scan(h) ; out = spikes @ W2^T  (spike rate ~0.1-0.2%)
//
// GEMM1 via f16 2-split on MFMA: a = a0 + a1/4096 (+ r ~ 2^-22|a|),
//   A.B^T ~= A0B0 + (A0B1s + A1sB0)/4096
// Round 11 source, 3rd resubmit (r11/r12 broker timeouts; r13 container failure pre-run).
// 3 dispatches. r10 lesson: staging shadow absorbs ONE operand's split (r8=69us), not two
// (r10=95us) -> W1 split reverts to prep (W1-only, 1024 blocks).
//   d1 prep_w1: W1 -> (B0,B1)
//   d2 gemm_rs (r8-exact, 69us proven) + W2T transpose rider blocks (r10-proven mechanism)
//   d3 scan_spmm: block b owns batch b: scan 1024 chains (masks in LDS only) + spmm rows
//      (t,b) in-place on d_out (disjoint rows per block; A reads before B writes).
// ws: [0,4M) W2T | [4M,6M) B0 | [6M,8M) B1  (needs 8 MiB; else fp32 fallback)

#define TT 128
#define BB 64
#define NN 1024
#define MROWS (TT * BB)          // 8192
#define SROW  (BB * NN)          // 65536
#define MiB   ((size_t)1048576)

typedef _Float16 h8  __attribute__((ext_vector_type(8)));
typedef _Float16 h4v __attribute__((ext_vector_type(4)));
typedef float    f4  __attribute__((ext_vector_type(4)));
typedef float    v2f __attribute__((ext_vector_type(2)));

#if __has_builtin(__builtin_elementwise_fma)
#define V2FMA(a, b, c) __builtin_elementwise_fma((a), (b), (c))
#else
static __device__ __forceinline__ v2f v2fma_(v2f a, v2f b, v2f c) {
    v2f r; r[0] = fmaf(a[0], b[0], c[0]); r[1] = fmaf(a[1], b[1], c[1]); return r;
}
#define V2FMA(a, b, c) v2fma_((a), (b), (c))
#endif

#define GL2LDS(g, l) __builtin_amdgcn_global_load_lds(                         \
    (const __attribute__((address_space(1))) void*)(const void*)(g),           \
    (__attribute__((address_space(3))) void*)(void*)(l), 16, 0, 0)

// ---------------- prep: split W1 only --------------------------------------------------------
__global__ __launch_bounds__(256) void prep_w1(const float* __restrict__ W1,
                                               _Float16* __restrict__ B0,
                                               _Float16* __restrict__ B1) {
    const int i = blockIdx.x * 256 + threadIdx.x;
    const float4 v = reinterpret_cast<const float4*>(W1)[i];
    const float f[4] = {v.x, v.y, v.z, v.w};
    h4v a0, a1;
#pragma unroll
    for (int j = 0; j < 4; ++j) {
        const _Float16 c = (_Float16)f[j];
        a0[j] = c;
        a1[j] = (_Float16)((f[j] - (float)c) * 4096.0f);  // scaled: no f16 subnormals
    }
    reinterpret_cast<h4v*>(B0)[i] = a0;
    reinterpret_cast<h4v*>(B1)[i] = a1;
}

// ---------------- MFMA GEMM (r8-exact) + W2T riders ------------------------------------------
// blocks 0..511: 128x128 tile, 4 waves (2x2), 16x16x32 f16 MFMA, K_STEP=32, dbuf LDS.
//   A reg-staged from fp32 x (T14 issue-early/write-late; split cvt rides post-MFMA shadow);
//   B0/B1 via global_load_lds with pre-swizzled source. LDS [row][k] f16, 64B rows = 4x16B
//   chunks, phys chunk = logical ^ ((row>>1)&3). XCD remap: p=(ib>>6)*8+(ib&7), cc=(ib>>3)&7.
// blocks 512..575: W2T transpose riders (16 32x32 tiles each).
__global__ __launch_bounds__(256, 2) void gemm_rs(const float* __restrict__ X,
                                                  const _Float16* __restrict__ B0g,
                                                  const _Float16* __restrict__ B1g,
                                                  const float* __restrict__ W2,
                                                  float* __restrict__ W2T,
                                                  float* __restrict__ C) {
    __shared__ _Float16 As0[2][4096], As1[2][4096];
    __shared__ _Float16 Bs0[2][4096], Bs1[2][4096];
    const int tid = threadIdx.x, lane = tid & 63, wid = tid >> 6;
    const int ib = blockIdx.x;

    if (ib >= 512) {   // ---- W2T transpose riders ----
        float* tile = (float*)&As0[0][0];          // 32x33 f32
        const int tx = tid & 31, ty = tid >> 5;    // 32 x 8
#pragma unroll 1
        for (int it = 0; it < 16; ++it) {
            const int tIdx = (ib - 512) * 16 + it;
            const int bx = (tIdx & 31) * 32, by = (tIdx >> 5) * 32;
#pragma unroll
            for (int j = 0; j < 32; j += 8)
                tile[(ty + j) * 33 + tx] = W2[(size_t)(by + ty + j) * NN + bx + tx];
            __syncthreads();
#pragma unroll
            for (int j = 0; j < 32; j += 8)
                W2T[(size_t)(bx + ty + j) * NN + by + tx] = tile[tx * 33 + ty + j];
            __syncthreads();
        }
        return;
    }

    const int wr = wid >> 1, wc = wid & 1;
    const int p  = ((ib >> 6) << 3) + (ib & 7);
    const int cc = (ib >> 3) & 7;
    const int rowBase = p * 128, colBase = cc * 128;

    // A reg-staging: row r = wid*32 + (lane>>2) (+16 second half), f16-chunk c = lane&3
    const int sr = wid * 32 + (lane >> 2);
    const int sc = lane & 3;
    const size_t xOff = (size_t)(rowBase + sr) * NN + sc * 8;
    const int wsw = (sc ^ ((sr >> 1) & 3)) << 3;          // rows r,r+16 share (r>>1)&3 (bit4 only)
    const int wA0 = sr * 32 + wsw;
    const int wA1 = (sr + 16) * 32 + wsw;

    // B staging (global_load_lds, source pre-swizzled)
    const int swzB = (((lane & 3) ^ ((sr >> 1) & 3)) << 3);
    const size_t bOff0 = (size_t)(colBase + sr) * NN + swzB;
    const size_t bOff1 = bOff0 + (size_t)16 * NN;
    const int l0 = wid * 1024, l1 = l0 + 512;

    // fragment read addrs: row, logical chunk = lane>>4, phys = logical ^ ((row>>1)&3)
    int fA[4], fB[4];
#pragma unroll
    for (int i = 0; i < 4; ++i) {
        const int ra = wr * 64 + i * 16 + (lane & 15);
        const int rb = wc * 64 + i * 16 + (lane & 15);
        fA[i] = ra * 32 + (((lane >> 4) ^ ((ra >> 1) & 3)) << 3);
        fB[i] = rb * 32 + (((lane >> 4) ^ ((rb >> 1) & 3)) << 3);
    }

    f4 acc0[4][4], acc1[4][4];
#pragma unroll
    for (int i = 0; i < 4; ++i)
#pragma unroll
        for (int j = 0; j < 4; ++j) { acc0[i][j] = (f4)0.0f; acc1[i][j] = (f4)0.0f; }

    f4 xa0, xa1, xb0, xb1;   // staged x: rows sr, sr+16 (k [8sc,8sc+8))

#define XLOAD(K0)                                              \
    do {                                                       \
        const size_t xo = xOff + (K0);                         \
        xa0 = *(const f4*)(X + xo);                            \
        xa1 = *(const f4*)(X + xo + 4);                        \
        xb0 = *(const f4*)(X + xo + (size_t)16 * NN);          \
        xb1 = *(const f4*)(X + xo + (size_t)16 * NN + 4);      \
    } while (0)

#define BSTAGE(bi, K0)                                         \
    do {                                                       \
        GL2LDS(B0g + bOff0 + (K0), &Bs0[bi][l0]);              \
        GL2LDS(B0g + bOff1 + (K0), &Bs0[bi][l1]);              \
        GL2LDS(B1g + bOff0 + (K0), &Bs1[bi][l0]);              \
        GL2LDS(B1g + bOff1 + (K0), &Bs1[bi][l1]);              \
    } while (0)

#define AWRITE(bi)                                                             \
    do {                                                                       \
        h8 hi, lo;                                                             \
        _Pragma("unroll") for (int e = 0; e < 4; ++e) {                        \
            const float f0 = xa0[e], f1 = xa1[e];                              \
            const _Float16 c0 = (_Float16)f0, c1 = (_Float16)f1;               \
            hi[e] = c0; hi[4 + e] = c1;                                        \
            lo[e]     = (_Float16)((f0 - (float)c0) * 4096.0f);                \
            lo[4 + e] = (_Float16)((f1 - (float)c1) * 4096.0f);                \
        }                                                                      \
        *(h8*)&As0[bi][wA0] = hi; *(h8*)&As1[bi][wA0] = lo;                    \
        _Pragma("unroll") for (int e = 0; e < 4; ++e) {                        \
            const float f0 = xb0[e], f1 = xb1[e];                              \
            const _Float16 c0 = (_Float16)f0, c1 = (_Float16)f1;               \
            hi[e] = c0; hi[4 + e] = c1;                                        \
            lo[e]     = (_Float16)((f0 - (float)c0) * 4096.0f);                \
            lo[4 + e] = (_Float16)((f1 - (float)c1) * 4096.0f);                \
        }                                                                      \
        *(h8*)&As0[bi][wA1] = hi; *(h8*)&As1[bi][wA1] = lo;                    \
    } while (0)

    XLOAD(0);
    BSTAGE(0, 0);
    AWRITE(0);
    __syncthreads();

    for (int t = 0; t < 32; ++t) {
        const int cur = t & 1;
        if (t < 31) {                    // issue next-tile loads EARLY (latency under MFMA)
            XLOAD((t + 1) * 32);
            BSTAGE(cur ^ 1, (t + 1) * 32);
        }
        h8 a0f[4], a1f[4], b0f[4], b1f[4];
#pragma unroll
        for (int i = 0; i < 4; ++i) {
            a0f[i] = *(const h8*)&As0[cur][fA[i]];
            a1f[i] = *(const h8*)&As1[cur][fA[i]];
            b0f[i] = *(const h8*)&Bs0[cur][fB[i]];
            b1f[i] = *(const h8*)&Bs1[cur][fB[i]];
        }
#pragma unroll
        for (int i = 0; i < 4; ++i)
#pragma unroll
            for (int j = 0; j < 4; ++j) {
                acc0[i][j] = __builtin_amdgcn_mfma_f32_16x16x32_f16(a0f[i], b0f[j], acc0[i][j], 0, 0, 0);
                acc1[i][j] = __builtin_amdgcn_mfma_f32_16x16x32_f16(a0f[i], b1f[j], acc1[i][j], 0, 0, 0);
                acc1[i][j] = __builtin_amdgcn_mfma_f32_16x16x32_f16(a1f[i], b0f[j], acc1[i][j], 0, 0, 0);
            }
        if (t < 31) AWRITE(cur ^ 1);     // write-late: cvt rides the post-MFMA shadow
        __syncthreads();
    }
#undef XLOAD
#undef BSTAGE
#undef AWRITE

    // C/D layout (m89-verified): col = lane&15, row = (lane>>4)*4 + reg
    const int orow = rowBase + wr * 64 + (lane >> 4) * 4;
    const int ocol = colBase + wc * 64 + (lane & 15);
#pragma unroll
    for (int i = 0; i < 4; ++i)
#pragma unroll
        for (int j = 0; j < 4; ++j)
#pragma unroll
            for (int q = 0; q < 4; ++q)
                C[(size_t)(orow + i * 16 + q) * NN + ocol + j * 16] =
                    acc0[i][j][q] + acc1[i][j][q] * (1.0f / 4096.0f);
}

// ---------------- fused LIF scan + sparse GEMM2 ----------------------------------------------
// Block b (64 blocks x 1024 threads) owns batch b. Phase A: thread=chain n, wave w = n>>6
// = mask word; exact reference arithmetic; masks -> LDS only (16 KB). Phase B: out rows
// (t*64+b) in-place on d_out (rows disjoint across blocks; A reads all before B writes).
// Summation order identical to prior spike_matmul (w asc, ffs asc) -> bitwise-same output.
__global__ __launch_bounds__(1024) void scan_spmm(const float* __restrict__ H,
                                                  const float* __restrict__ W2T,
                                                  float* __restrict__ out) {
    __shared__ unsigned long long msk[TT * 16];    // [t][word], 16 KB
    const int b = blockIdx.x;
    const int tid = threadIdx.x;                   // = n
    const int w = tid >> 6;
    const bool lane0 = (tid & 63) == 0;

    // ---- phase A: scan ----
    const float* Hb = H + (size_t)b * NN + tid;
    float v = 0.0f;
    float buf[16];
#pragma unroll
    for (int j = 0; j < 16; ++j) buf[j] = Hb[(size_t)j * SROW];

    for (int t0 = 0; t0 < TT; t0 += 16) {
        float nbuf[16];
        if (t0 + 16 < TT) {
#pragma unroll
            for (int j = 0; j < 16; ++j) nbuf[j] = Hb[(size_t)(t0 + 16 + j) * SROW];
        } else {
#pragma unroll
            for (int j = 0; j < 16; ++j) nbuf[j] = 0.f;
        }
#pragma unroll
        for (int j = 0; j < 16; ++j) {
            const float x = buf[j];
            const float h = v + (x - v) * 0.5f;
            const bool s = (h >= 1.0f);
            v = s ? 0.0f : h;
            const unsigned long long m = __ballot(s);
            if (lane0) msk[(t0 + j) * 16 + w] = m;
        }
#pragma unroll
        for (int j = 0; j < 16; ++j) buf[j] = nbuf[j];
    }
    __syncthreads();

    // ---- phase B: spmm, thread owns output column tid ----
#pragma unroll 1
    for (int t = 0; t < TT; ++t) {
        float acc = 0.f;
#pragma unroll 1
        for (int ww = 0; ww < 16; ++ww) {
            unsigned long long bits = msk[t * 16 + ww];   // LDS broadcast
            while (bits) {
                const int n2 = ww * 64 + (__ffsll(bits) - 1);
                bits &= bits - 1;
                acc += W2T[(size_t)n2 * NN + tid];
            }
        }
        out[((size_t)t * BB + b) * NN + tid] = acc;
    }
}

// ---------------- W2 transpose (fallback path only) -----------------------------------------
__global__ __launch_bounds__(256) void transpose_nn(const float* __restrict__ in,
                                                    float* __restrict__ out) {
    __shared__ float tile[32][33];
    const int bx = blockIdx.x * 32, by = blockIdx.y * 32;
    const int tx = threadIdx.x, ty = threadIdx.y;
#pragma unroll
    for (int j = 0; j < 32; j += 8)
        tile[ty + j][tx] = in[(size_t)(by + ty + j) * NN + bx + tx];
    __syncthreads();
#pragma unroll
    for (int j = 0; j < 32; j += 8)
        out[(size_t)(bx + ty + j) * NN + by + tx] = tile[tx][ty + j];
}

// ---------------- fallback fp32 GEMM (used only if ws too small) -----------------------------
#define BM 128
#define BN 64
#define BK 16
__global__ __launch_bounds__(256, 4) void gemm1_f32(const float* __restrict__ A,
                                                    const float* __restrict__ B,
                                                    float* __restrict__ C) {
    __shared__ float Asb[2][BK][132];
    __shared__ float Bsb[2][BK][68];
    const int tid = threadIdx.x;
    const int ty = tid >> 4;
    const int tx = tid & 15;
    const int rowBase = blockIdx.y * BM;
    const int colBase = blockIdx.x * BN;
    const int sr = tid >> 2;
    const int sk = (tid & 3) * 4;

    const float* Ap0 = A + (size_t)(rowBase + sr) * NN + sk;
    const float* Ap1 = Ap0 + (size_t)64 * NN;
    const float* Bp  = B + (size_t)(colBase + sr) * NN + sk;

    v2f acc[4][4];
#pragma unroll
    for (int i = 0; i < 4; ++i)
#pragma unroll
        for (int j = 0; j < 4; ++j) acc[i][j] = (v2f){0.f, 0.f};

    float4 ra0 = *(const float4*)Ap0;
    float4 ra1 = *(const float4*)Ap1;
    float4 rb  = *(const float4*)Bp;

#define STW(buf)                                                                       \
    do {                                                                               \
        Asb[buf][sk + 0][sr] = ra0.x; Asb[buf][sk + 1][sr] = ra0.y;                    \
        Asb[buf][sk + 2][sr] = ra0.z; Asb[buf][sk + 3][sr] = ra0.w;                    \
        Asb[buf][sk + 0][sr + 64] = ra1.x; Asb[buf][sk + 1][sr + 64] = ra1.y;          \
        Asb[buf][sk + 2][sr + 64] = ra1.z; Asb[buf][sk + 3][sr + 64] = ra1.w;          \
        Bsb[buf][sk + 0][sr] = rb.x;  Bsb[buf][sk + 1][sr] = rb.y;                     \
        Bsb[buf][sk + 2][sr] = rb.z;  Bsb[buf][sk + 3][sr] = rb.w;                     \
    } while (0)

    STW(0);
    __syncthreads();
    const int NT = NN / BK;
    for (int t = 0; t < NT; ++t) {
        const int cur = t & 1;
        if (t < NT - 1) {
            const int ko = (t + 1) * BK;
            ra0 = *(const float4*)(Ap0 + ko);
            ra1 = *(const float4*)(Ap1 + ko);
            rb  = *(const float4*)(Bp + ko);
        }
#pragma unroll
        for (int k = 0; k < BK; ++k) {
            const v2f* ap = (const v2f*)&Asb[cur][k][ty * 8];
            const float4 bf = *(const float4*)&Bsb[cur][k][tx * 4];
            const float bb[4] = {bf.x, bf.y, bf.z, bf.w};
            const v2f a0 = ap[0], a1 = ap[1], a2 = ap[2], a3 = ap[3];
#pragma unroll
            for (int j = 0; j < 4; ++j) {
                const v2f bd = {bb[j], bb[j]};
                acc[0][j] = V2FMA(a0, bd, acc[0][j]);
                acc[1][j] = V2FMA(a1, bd, acc[1][j]);
                acc[2][j] = V2FMA(a2, bd, acc[2][j]);
                acc[3][j] = V2FMA(a3, bd, acc[3][j]);
            }
        }
        if (t < NT - 1) STW(cur ^ 1);
        __syncthreads();
    }
#undef STW
    float* Cp = C + (size_t)(rowBase + ty * 8) * NN + colBase + tx * 4;
#pragma unroll
    for (int rp = 0; rp < 4; ++rp) {
        float4 lo = {acc[rp][0][0], acc[rp][1][0], acc[rp][2][0], acc[rp][3][0]};
        float4 hi = {acc[rp][0][1], acc[rp][1][1], acc[rp][2][1], acc[rp][3][1]};
        *(float4*)(Cp + (size_t)(2 * rp) * NN)     = lo;
        *(float4*)(Cp + (size_t)(2 * rp + 1) * NN) = hi;
    }
}

extern "C" void kernel_launch(void* const* d_in, const int* in_sizes, int n_in,
                              void* d_out, int out_size, void* d_ws, size_t ws_size,
                              hipStream_t stream) {
    const float* x  = (const float*)d_in[0];
    const float* W1 = (const float*)d_in[1];
    const float* W2 = (const float*)d_in[2];
    float* out = (float*)d_out;

    float* W2T = (float*)d_ws;                               // 4 MiB

    if (ws_size >= 8 * MiB) {
        _Float16* B0 = (_Float16*)((char*)d_ws + 4 * MiB);   // 2 MiB
        _Float16* B1 = (_Float16*)((char*)d_ws + 6 * MiB);   // 2 MiB

        prep_w1<<<1024, 256, 0, stream>>>(W1, B0, B1);
        gemm_rs<<<576, 256, 0, stream>>>(x, B0, B1, W2, W2T, out);
    } else {
        transpose_nn<<<dim3(32, 32), dim3(32, 8), 0, stream>>>(W2, W2T);
        gemm1_f32<<<dim3(NN / BN, MROWS / BM), 256, 0, stream>>>(x, W1, out);
    }
    scan_spmm<<<BB, 1024, 0, stream>>>(out, W2T, out);
}